// Round 4
// baseline (5867.878 us; speedup 1.0000x reference)
//
#include <hip/hip_runtime.h>
#include <hip/hip_bf16.h>

#define Bb 512
#define Dd 1024
#define Hh 2048
#define BH_ (Bb*Hh)
#define BD_ (Bb*Dd)
#define NTICK 5760   // 9 step-equivalents x (256 + 256 + 128) tickets

typedef unsigned short u16;
typedef __attribute__((ext_vector_type(8))) short short8;
typedef __attribute__((ext_vector_type(4))) float f32x4;

enum { M_F32 = 0, M_IN, M_SIG, M_SQRELU, M_MIX, M_BF16, M_DRIFT, M_FINAL };

struct GemmP {
    const u16* A[5];
    const u16* W[5];     // transposed weights, N x K, bf16
    void* dst[5];
    int mode[5];
    int M, N, K;
    int S;               // block-level split-K factor (1,2,4); grid.x = (N/64)*S
    int* tick;           // per-tile tickets for this launch (S>1)
    float* part;         // partial scratch: [tile][S][4096] f32
    int dstride;         // dst row stride for M_BF16
    const int* done;
    // epilogue extras
    const float* bias;
    const float* mk; const float* mv; const float* mr; const float* mk2v; const float* mr2v;
    float* xx; float* cc;                 // planar shadow state (loop)
    const float* lstate;                  // original interleaved state (final) or null
    float* liF;                           // Li plane (loop)
    float* stateOut;                      // d_out next_state base (final)
    u16 *o1, *o2, *o3, *o4, *o5;          // Xk,Xv,Xr,Xk2,Xr2
    // fused-mix extras (M_MIX)
    const float* Kp; const float* Vp; const float* Rp;
    float* aa; float* bbp; float* ppp;
    const float* Li;
    const float* tf; const float* td;
    const float* R2;
    u16* acat35;                          // [512][4096]: Rw | V2 (bf16), mix writes both
    float* drift; float* accAbs; float* accSq;
    float* scal; int nticket;             // ticket-folded stepfin (M_DRIFT only)
    const float* enc; const float* bout; float* dout;
    const float* sc; u16* acat;           // M_DRIFT maintains Acat's sc+drift half
};

#define GLDS16(gp, lp) __builtin_amdgcn_global_load_lds( \
    (const __attribute__((address_space(1))) void*)(gp), \
    (__attribute__((address_space(3))) void*)(lp), 16, 0, 0)

// ---- 64x64 tile, 512 threads (8 waves), in-block split-K x2, BK=64 dbuf ----
// Optional block-level split-K (p.S): blockIdx.x encodes (tile-x, K-slot).
// Each block computes K/S; partials merged deterministically (fixed slot
// order) by the last-arriving block per tile, which also runs the epilogue.
__global__ __launch_bounds__(512, 2) void gemm_sk(GemmP p) {
    if (p.done && *(volatile const int*)p.done) return;
    const int z = blockIdx.z;
    const int S = p.S;
    const int nbx = gridDim.x / S;
    const int kb2 = blockIdx.x % S;            // K-slot of this block
    const int bx  = blockIdx.x / S;
    const u16* __restrict__ A = p.A[z];
    const u16* __restrict__ W = p.W[z];
    const int Kd = p.K;
    const int Klen = Kd / S;
    const int m0 = blockIdx.y * 64, n0 = bx * 64;

    __shared__ alignas(16) u16 smem[4][64 * 64];   // A0, A1, B0, B1 = 32 KiB

    const int t = threadIdx.x;
    const int l = t & 63, w = t >> 6;              // 8 waves
    const int lane16 = l & 15, quad = l >> 4;
    const int wq = w & 3, kg = w >> 2;
    const int wm = wq & 1, wn = wq >> 1;

    // staging: thread t owns row t>>3, linear 16B chunk t&7, swizzled source
    const int srow = t >> 3, sc8 = t & 7;
    const int scs = sc8 ^ (srow & 7);
    const u16* ag = A + (size_t)(m0 + srow) * Kd + (size_t)kb2 * Klen + scs * 8;
    const u16* bg = W + (size_t)(n0 + srow) * Kd + (size_t)kb2 * Klen + scs * 8;

    f32x4 zero = {0.f, 0.f, 0.f, 0.f};
    f32x4 acc[2][2];
    acc[0][0] = zero; acc[0][1] = zero; acc[1][0] = zero; acc[1][1] = zero;

    // prologue: stage slab 0 into buf 0 (syncthreads drains vmcnt)
    GLDS16(ag, &smem[0][512 * w]);
    GLDS16(bg, &smem[2][512 * w]);
    __syncthreads();

    int buf = 0;
    for (int k0 = 0; k0 < Klen; k0 += 64) {
        if (k0 + 64 < Klen) {
            const int nb = buf ^ 1;
            GLDS16(ag + k0 + 64, &smem[nb][512 * w]);
            GLDS16(bg + k0 + 64, &smem[2 + nb][512 * w]);
        }
        const u16* As = smem[buf];
        const u16* Bs = smem[2 + buf];
        const int cg = kg * 4 + quad;              // this wave's 16B chunk in slab
        const int ra0 = wm * 32 + lane16, ra1 = ra0 + 16;
        const int rb0 = wn * 32 + lane16, rb1 = rb0 + 16;
        short8 af0 = *(const short8*)(const void*)&As[ra0 * 64 + ((cg ^ (ra0 & 7)) << 3)];
        short8 af1 = *(const short8*)(const void*)&As[ra1 * 64 + ((cg ^ (ra1 & 7)) << 3)];
        short8 bf0 = *(const short8*)(const void*)&Bs[rb0 * 64 + ((cg ^ (rb0 & 7)) << 3)];
        short8 bf1 = *(const short8*)(const void*)&Bs[rb1 * 64 + ((cg ^ (rb1 & 7)) << 3)];
        acc[0][0] = __builtin_amdgcn_mfma_f32_16x16x32_bf16(af0, bf0, acc[0][0], 0, 0, 0);
        acc[0][1] = __builtin_amdgcn_mfma_f32_16x16x32_bf16(af0, bf1, acc[0][1], 0, 0, 0);
        acc[1][0] = __builtin_amdgcn_mfma_f32_16x16x32_bf16(af1, bf0, acc[1][0], 0, 0, 0);
        acc[1][1] = __builtin_amdgcn_mfma_f32_16x16x32_bf16(af1, bf1, acc[1][1], 0, 0, 0);
        __syncthreads();
        buf ^= 1;
    }

    // ---- cross-wave-group partial merge via LDS (17-float pad per lane) ----
    float* red = (float*)smem;
    const int rbase = wq * 1088 + l * 17;
    if (kg == 1) {
#pragma unroll
        for (int sm = 0; sm < 2; ++sm)
#pragma unroll
            for (int sn = 0; sn < 2; ++sn)
#pragma unroll
                for (int i = 0; i < 4; ++i)
                    red[rbase + (sm * 2 + sn) * 4 + i] = acc[sm][sn][i];
    }
    __syncthreads();
    if (kg == 0) {
#pragma unroll
        for (int sm = 0; sm < 2; ++sm)
#pragma unroll
            for (int sn = 0; sn < 2; ++sn)
#pragma unroll
                for (int i = 0; i < 4; ++i)
                    acc[sm][sn][i] += red[rbase + (sm * 2 + sn) * 4 + i];
    }

    // ---- block-level split-K merge (deterministic fixed-order sum) ----
    if (S > 1) {
        const int tileId = (z * (int)gridDim.y + (int)blockIdx.y) * nbx + bx;
        float* slotBase = p.part + (size_t)tileId * S * 4096;
        if (kg == 0) {
            float* q = slotBase + (size_t)kb2 * 4096 + (wq * 64 + l) * 16;
#pragma unroll
            for (int sm = 0; sm < 2; ++sm)
#pragma unroll
                for (int sn = 0; sn < 2; ++sn)
#pragma unroll
                    for (int i = 0; i < 4; ++i)
                        q[(sm * 2 + sn) * 4 + i] = acc[sm][sn][i];
        }
        __threadfence();
        __syncthreads();                 // all partial stores fenced
        if (t == 0) ((int*)smem)[0] = atomicAdd(p.tick + tileId, 1);
        __syncthreads();
        const int ret = ((int*)smem)[0];
        if (ret != S - 1) return;        // winner blocks done; loser merges
        __threadfence();                 // acquire before reading partials
        if (kg == 0) {
            const float* qb = slotBase + (wq * 64 + l) * 16;
#pragma unroll
            for (int sm = 0; sm < 2; ++sm)
#pragma unroll
                for (int sn = 0; sn < 2; ++sn)
#pragma unroll
                    for (int i = 0; i < 4; ++i) {
                        const int j = (sm * 2 + sn) * 4 + i;
                        float tot = 0.f;
                        for (int s2 = 0; s2 < S; ++s2) {
                            float pv = (s2 == kb2) ? acc[sm][sn][i]
                                : __hip_atomic_load(qb + (size_t)s2 * 4096 + j,
                                                    __ATOMIC_RELAXED, __HIP_MEMORY_SCOPE_AGENT);
                            tot += pv;
                        }
                        acc[sm][sn][i] = tot;
                    }
        }
    }

    const int mode = p.mode[z];
    float sabs = 0.f, ssq = 0.f;
    if (kg == 0) {
#pragma unroll
        for (int sm = 0; sm < 2; ++sm)
#pragma unroll
            for (int sn = 0; sn < 2; ++sn)
#pragma unroll
                for (int i = 0; i < 4; ++i) {
                    const int m = m0 + wm * 32 + sm * 16 + quad * 4 + i;
                    const int n = n0 + wn * 32 + sn * 16 + lane16;
                    const size_t idx = (size_t)m * p.N + n;
                    const float v = acc[sm][sn][i];
                    if (mode == M_F32) {
                        ((float*)p.dst[z])[idx] = v;
                    } else if (mode == M_IN) {
                        float li = fminf(fmaxf(v + p.bias[n], -50.f), 50.f);
                        float xxv, ccv;
                        if (p.lstate) { xxv = p.lstate[idx * 5 + 0]; ccv = p.lstate[idx * 5 + 4]; }
                        else { xxv = p.xx[idx]; ccv = p.cc[idx]; }
                        float mk = p.mk[n], mv = p.mv[n], mr = p.mr[n], mk2 = p.mk2v[n], mr2 = p.mr2v[n];
                        ((__hip_bfloat16*)p.o1)[idx] = __float2bfloat16(li * mk + xxv * (1.f - mk));
                        ((__hip_bfloat16*)p.o2)[idx] = __float2bfloat16(li * mv + xxv * (1.f - mv));
                        ((__hip_bfloat16*)p.o3)[idx] = __float2bfloat16(li * mr + xxv * (1.f - mr));
                        ((__hip_bfloat16*)p.o4)[idx] = __float2bfloat16(li * mk2 + ccv * (1.f - mk2));
                        ((__hip_bfloat16*)p.o5)[idx] = __float2bfloat16(li * mr2 + ccv * (1.f - mr2));
                        if (p.lstate) { p.stateOut[idx * 5 + 0] = li; p.stateOut[idx * 5 + 4] = li; }
                        else p.liF[idx] = li;
                    } else if (mode == M_SIG) {
                        ((float*)p.dst[z])[idx] = 1.f / (1.f + __expf(-v));
                    } else if (mode == M_SQRELU) {
                        float r = fmaxf(v, 0.f);
                        ((__hip_bfloat16*)p.dst[z])[idx] = __float2bfloat16(r * r);
                    } else if (mode == M_BF16) {
                        ((__hip_bfloat16*)p.dst[z])[(size_t)m * p.dstride + n] = __float2bfloat16(v);
                    } else if (mode == M_MIX) {
                        // fused RWKV wkv + state update; writes Rw and V2 into acat35
                        float k = p.Kp[idx], vv = p.Vp[idx], rpre = p.Rp[idx];
                        float a, b, P;
                        if (p.lstate) { a = p.lstate[idx * 5 + 1]; b = p.lstate[idx * 5 + 2]; P = p.lstate[idx * 5 + 3]; }
                        else { a = p.aa[idx]; b = p.bbp[idx]; P = p.ppp[idx]; }
                        float r = 1.f / (1.f + __expf(-rpre));
                        float ww = p.tf[n] + k;
                        float q = fmaxf(P, ww);
                        float e1 = __expf(P - q), e2 = __expf(ww - q);
                        float wkv = (e1 * a + e2 * vv) / (e1 * b + e2);
                        const size_t i35 = (size_t)m * 4096 + n;
                        ((__hip_bfloat16*)p.acat35)[i35] = __float2bfloat16(r * wkv);
                        ((__hip_bfloat16*)p.acat35)[i35 + 2048] = __float2bfloat16(p.R2[idx] * v);
                        float ww2 = P - __expf(p.td[n]);
                        float q2 = fmaxf(ww2, k);
                        float e1b = __expf(ww2 - q2), e2b = __expf(k - q2);
                        float na  = fminf(fmaxf(e1b * a + e2b * vv, -50.f), 50.f);
                        float nb2 = fminf(fmaxf(e1b * b + e2b, -50.f), 50.f);
                        float nq  = fminf(fmaxf(q2, -50.f), 50.f);
                        if (p.lstate) {
                            p.stateOut[idx * 5 + 1] = na; p.stateOut[idx * 5 + 2] = nb2; p.stateOut[idx * 5 + 3] = nq;
                        } else {
                            p.aa[idx] = na; p.bbp[idx] = nb2; p.ppp[idx] = nq;
                            float li = p.Li[idx];
                            p.xx[idx] = li; p.cc[idx] = li;
                        }
                    } else if (mode == M_DRIFT) {
                        float d = tanhf(v);
                        float nd = fminf(fmaxf(p.drift[idx] + d, -5.f), 5.f);
                        p.drift[idx] = nd;
                        ((__hip_bfloat16*)p.acat)[(size_t)m * 2048 + 1024 + n] = __float2bfloat16(p.sc[idx] + nd);
                        sabs += fabsf(d);
                        ssq += nd * nd;
                    } else { // M_FINAL
                        p.dout[idx] = p.enc[idx] + v + p.bout[n];
                    }
                }
    }

    if (mode == M_DRIFT) {
        if (kg == 0) {
#pragma unroll
            for (int off = 32; off > 0; off >>= 1) {
                sabs += __shfl_down(sabs, off, 64);
                ssq += __shfl_down(ssq, off, 64);
            }
            if (l == 0) { atomicAdd(p.accAbs, sabs); atomicAdd(p.accSq, ssq); }
        }
        __syncthreads();
        if (t == 0) {   // last-tile ticket performs the per-step scalar finalize
            __threadfence();
            int vtk = atomicAdd((int*)(p.scal + 5), 1);
            if (vtk == p.nticket - 1) {
                volatile float* s = p.scal;
                float hinge = fminf(fmaxf(s[4] / (float)Bb - 0.1f, 0.f), 100.f);
                s[1] = s[1] + hinge;
                s[2] = s[2] + 1.f;
                if (s[3] / (float)BD_ < 0.01f) ((volatile int*)p.scal)[0] = 1;
                s[3] = 0.f; s[4] = 0.f;
                ((volatile int*)p.scal)[5] = 0;
            }
        }
    }
}

// ---------------- z-batched transpose f32 (KxN) -> bf16 (NxK) ----------------
struct TP { const float* src[7]; u16* dst[7]; int K; int N; };

__global__ void transposeWz(TP tp) {
    __shared__ float tile[32][33];
    const float* __restrict__ src = tp.src[blockIdx.z];
    u16* __restrict__ dst = tp.dst[blockIdx.z];
    int kt = blockIdx.y * 32, nt = blockIdx.x * 32;
    int tx = threadIdx.x, ty = threadIdx.y;
#pragma unroll
    for (int j = 0; j < 4; j++)
        tile[ty + j * 8][tx] = src[(size_t)(kt + ty + j * 8) * tp.N + nt + tx];
    __syncthreads();
    __hip_bfloat16* d = (__hip_bfloat16*)dst;
#pragma unroll
    for (int j = 0; j < 4; j++)
        d[(size_t)(nt + ty + j * 8) * tp.K + kt + tx] = __float2bfloat16(tile[tx][ty + j * 8]);
}

// ---------------- f32 -> bf16 row-major cast (Wo) ----------------
__global__ void castW(const float* __restrict__ src, u16* __restrict__ dst, int nelem) {
    int i = blockIdx.x * 256 + threadIdx.x;
    if (i < nelem) ((__hip_bfloat16*)dst)[i] = __float2bfloat16(src[i]);
}

// ---------------- copy WdT/WoutT into the K>=2048 half of W35/W35F ----------------
struct CP { const u16* src[2]; u16* dst[2]; };
__global__ void copyTail(CP cp) {
    int i = blockIdx.x * 256 + threadIdx.x;     // over 1024*2048
    if (i >= Dd * Hh) return;
    const u16* s = cp.src[blockIdx.z];
    u16* d = cp.dst[blockIdx.z];
    int m = i >> 11, k = i & 2047;
    d[(size_t)m * 4096 + 2048 + k] = s[i];
}

// ---------------- per-call init: planarize state, drift, scalars, Acat, tickets ----------------
__global__ void initstate(const float* __restrict__ lstate, const float* __restrict__ idrift,
                          const float* __restrict__ enc, const float* __restrict__ sc,
                          float* xx, float* aa, float* bb, float* pp, float* cc,
                          float* drift, float* scal, u16* acat, int* tick) {
    int i = blockIdx.x * 256 + threadIdx.x;
    if (i < BH_) {
        const float* s = lstate + (size_t)i * 5;
        xx[i] = s[0]; aa[i] = s[1]; bb[i] = s[2]; pp[i] = s[3]; cc[i] = s[4];
    }
    if (i < BD_) {
        drift[i] = idrift[i];
        int m = i >> 10, d = i & 1023;
        __hip_bfloat16* Ab = (__hip_bfloat16*)acat;
        Ab[(size_t)m * 2048 + d] = __float2bfloat16(enc[i]);
        Ab[(size_t)m * 2048 + 1024 + d] = __float2bfloat16(sc[i] + idrift[i]);
    }
    if (i < NTICK) tick[i] = 0;
    if (i == 0) {
        ((int*)scal)[0] = 0; scal[1] = 0.f; scal[2] = 0.f; scal[3] = 0.f; scal[4] = 0.f;
        ((int*)scal)[5] = 0;
    }
}

// ---------------- tail: commitment scalar + drift copy ----------------
__global__ void tailk(const float* __restrict__ scal, const float* __restrict__ drift, float* __restrict__ dout) {
    int i = blockIdx.x * 256 + threadIdx.x;
    const size_t OC = (size_t)BD_ + (size_t)5 * BH_;
    if (i == 0) dout[OC] = scal[1] / fmaxf(scal[2], 1.f);
    if (i < BD_) dout[OC + 1 + i] = drift[i];
}

extern "C" void kernel_launch(void* const* d_in, const int* in_sizes, int n_in,
                              void* d_out, int out_size, void* d_ws, size_t ws_size,
                              hipStream_t stream) {
    const float* enc    = (const float*)d_in[0];
    const float* sc     = (const float*)d_in[1];
    const float* lstate = (const float*)d_in[2];
    const float* idrift = (const float*)d_in[3];
    const float* Win    = (const float*)d_in[4];
    const float* b_in   = (const float*)d_in[5];
    const float* Wdrift = (const float*)d_in[6];
    const float* Wout   = (const float*)d_in[7];
    const float* b_out  = (const float*)d_in[8];
    const float* mix_k  = (const float*)d_in[9];
    const float* mix_v  = (const float*)d_in[10];
    const float* mix_r  = (const float*)d_in[11];
    const float* mix_k2 = (const float*)d_in[12];
    const float* mix_r2 = (const float*)d_in[13];
    const float* tdec   = (const float*)d_in[14];
    const float* tfirst = (const float*)d_in[15];
    const float* Wk  = (const float*)d_in[16];
    const float* Wv  = (const float*)d_in[17];
    const float* Wr  = (const float*)d_in[18];
    const float* Wo  = (const float*)d_in[19];
    const float* Wk2 = (const float*)d_in[20];
    const float* Wv2 = (const float*)d_in[21];
    const float* Wr2 = (const float*)d_in[22];
    float* dout = (float*)d_out;

    const size_t BHs = (size_t)Bb * Hh;
    const size_t BDs = (size_t)Bb * Dd;
    const size_t PART = (size_t)512 * 4096;       // 2M floats = 8 MB scratch

    const size_t need_f32 = 10 * BHs + BDs + 16 + PART + 8192;
    const size_t need_u16 = (size_t)2 * Dd * Hh + 6 * (size_t)Hh * Hh + 2 * (size_t)Hh * Dd
                          + 2 * (size_t)Dd * 4096 + 7 * BHs + (size_t)Bb * 4096;
    const size_t need_bytes = need_f32 * 4 + need_u16 * 2;
    if (ws_size < need_bytes) return;

    float* f = (float*)d_ws;
    float* xx  = f;
    float* aa  = xx + BHs;
    float* bbp = aa + BHs;
    float* ppp = bbp + BHs;
    float* cc  = ppp + BHs;
    float* Li  = cc + BHs;
    float* Kp  = Li + BHs;
    float* Vp  = Kp + BHs;
    float* Rp  = Vp + BHs;
    float* R2  = Rp + BHs;
    float* drift = R2 + BHs;
    float* scal  = drift + BDs;
    float* part  = scal + 16;
    int*   tick  = (int*)(part + PART);
    u16* u = (u16*)(tick + 8192);
    u16* WinT  = u; u += (size_t)2 * Dd * Hh;
    u16* WkT   = u; u += (size_t)Hh * Hh;
    u16* WvT   = u; u += (size_t)Hh * Hh;
    u16* WrT   = u; u += (size_t)Hh * Hh;
    u16* Wk2T  = u; u += (size_t)Hh * Hh;
    u16* Wv2T  = u; u += (size_t)Hh * Hh;
    u16* Wr2T  = u; u += (size_t)Hh * Hh;
    u16* WdT   = u; u += (size_t)Hh * Dd;
    u16* WoutT = u; u += (size_t)Hh * Dd;
    u16* W35   = u; u += (size_t)Dd * 4096;   // [1024][4096]: WoWdT | WdT
    u16* W35F  = u; u += (size_t)Dd * 4096;   // [1024][4096]: WoWoutT | WoutT
    u16* Acat  = u; u += BHs;                 // [512][2048]: enc | sc+drift
    u16* Xk    = u; u += BHs;
    u16* Xv    = u; u += BHs;
    u16* Xr    = u; u += BHs;
    u16* Xk2   = u; u += BHs;
    u16* Xr2   = u; u += BHs;
    u16* Kk    = u; u += BHs;
    u16* Acat35 = u; u += (size_t)Bb * 4096;  // [512][4096]: Rw | V2
    u16* Wo_bf = Xk;                          // alias: Wo cast (4M ele over Xk..Xk2), dead before step 0

    int* doneptr = (int*)scal;
    float* accAbs = scal + 3;
    float* accSq  = scal + 4;

    dim3 tb(32, 8);
    TP tpa = {};
    tpa.src[0] = Wk;  tpa.dst[0] = WkT;
    tpa.src[1] = Wv;  tpa.dst[1] = WvT;
    tpa.src[2] = Wr;  tpa.dst[2] = WrT;
    tpa.src[3] = Wk2; tpa.dst[3] = Wk2T;
    tpa.src[4] = Wv2; tpa.dst[4] = Wv2T;
    tpa.src[5] = Wr2; tpa.dst[5] = Wr2T;
    tpa.K = Hh; tpa.N = Hh;
    transposeWz<<<dim3(Hh / 32, Hh / 32, 6), tb, 0, stream>>>(tpa);
    TP tpb = {};
    tpb.src[0] = Win; tpb.dst[0] = WinT; tpb.K = 2 * Dd; tpb.N = Hh;
    transposeWz<<<dim3(Hh / 32, (2 * Dd) / 32, 1), tb, 0, stream>>>(tpb);
    TP tpc = {};
    tpc.src[0] = Wdrift; tpc.dst[0] = WdT;
    tpc.src[1] = Wout;   tpc.dst[1] = WoutT;
    tpc.K = Hh; tpc.N = Dd;
    transposeWz<<<dim3(Dd / 32, Hh / 32, 2), tb, 0, stream>>>(tpc);

    castW<<<(Hh * Hh + 255) / 256, 256, 0, stream>>>(Wo, Wo_bf, Hh * Hh);

    initstate<<<(BH_ + 255) / 256, 256, 0, stream>>>(lstate, idrift, enc, sc,
                                                     xx, aa, bbp, ppp, cc, drift, scal, Acat, tick);

    // ---- one-time weight products: W35 = [ (Wo@Wd)^T | WdT ], W35F = [ (Wo@Wout)^T | WoutT ] ----
    GemmP pp = {};
    pp.A[0] = WdT;   pp.W[0] = Wo_bf; pp.mode[0] = M_BF16; pp.dst[0] = W35;
    pp.A[1] = WoutT; pp.W[1] = Wo_bf; pp.mode[1] = M_BF16; pp.dst[1] = W35F;
    pp.M = Dd; pp.N = Hh; pp.K = Hh; pp.S = 1; pp.dstride = 4096;
    gemm_sk<<<dim3(Hh / 64, Dd / 64, 2), 512, 0, stream>>>(pp);

    CP cpt = {};
    cpt.src[0] = WdT;   cpt.dst[0] = W35;
    cpt.src[1] = WoutT; cpt.dst[1] = W35F;
    copyTail<<<dim3((Dd * Hh + 255) / 256, 1, 2), 256, 0, stream>>>(cpt);

    // ---- GEMM descriptors ----
    GemmP g1 = {};
    g1.A[0] = Acat; g1.W[0] = WinT; g1.mode[0] = M_IN;
    g1.M = Bb; g1.N = Hh; g1.K = 2 * Dd; g1.S = 2; g1.part = part;
    g1.done = doneptr;
    g1.bias = b_in; g1.mk = mix_k; g1.mv = mix_v; g1.mr = mix_r; g1.mk2v = mix_k2; g1.mr2v = mix_r2;
    g1.xx = xx; g1.cc = cc; g1.liF = Li;
    g1.o1 = Xk; g1.o2 = Xv; g1.o3 = Xr; g1.o4 = Xk2; g1.o5 = Xr2;

    GemmP g2 = {};
    g2.A[0] = Xk;  g2.W[0] = WkT;  g2.mode[0] = M_F32;    g2.dst[0] = Kp;
    g2.A[1] = Xv;  g2.W[1] = WvT;  g2.mode[1] = M_F32;    g2.dst[1] = Vp;
    g2.A[2] = Xr;  g2.W[2] = WrT;  g2.mode[2] = M_F32;    g2.dst[2] = Rp;
    g2.A[3] = Xr2; g2.W[3] = Wr2T; g2.mode[3] = M_SIG;    g2.dst[3] = R2;
    g2.A[4] = Xk2; g2.W[4] = Wk2T; g2.mode[4] = M_SQRELU; g2.dst[4] = Kk;
    g2.M = Bb; g2.N = Hh; g2.K = Hh; g2.S = 1;
    g2.done = doneptr;

    GemmP g2b = {};
    g2b.A[0] = Kk; g2b.W[0] = Wv2T; g2b.mode[0] = M_MIX;
    g2b.M = Bb; g2b.N = Hh; g2b.K = Hh; g2b.S = 2; g2b.part = part;
    g2b.done = doneptr;
    g2b.Kp = Kp; g2b.Vp = Vp; g2b.Rp = Rp;
    g2b.aa = aa; g2b.bbp = bbp; g2b.ppp = ppp;
    g2b.xx = xx; g2b.cc = cc; g2b.Li = Li;
    g2b.tf = tfirst; g2b.td = tdec;
    g2b.R2 = R2; g2b.acat35 = Acat35;

    GemmP g35 = {};
    g35.A[0] = Acat35; g35.W[0] = W35; g35.mode[0] = M_DRIFT;
    g35.M = Bb; g35.N = Dd; g35.K = 4096; g35.S = 4; g35.part = part;
    g35.done = doneptr;
    g35.drift = drift; g35.accAbs = accAbs; g35.accSq = accSq;
    g35.scal = scal; g35.nticket = (Dd / 64) * (Bb / 64);   // 128 tiles
    g35.sc = sc; g35.acat = Acat;

    dim3 gH2(2 * Hh / 64, Bb / 64, 1);   // 64 x 8 = 512 blocks (S=2)
    dim3 gH5(Hh / 64, Bb / 64, 5);       // 1280 blocks (S=1)
    dim3 gD4(4 * Dd / 64, Bb / 64, 1);   // 64 x 8 = 512 blocks (S=4)

    for (int s = 0; s < 8; ++s) {
        g1.tick  = tick + s * 640;
        g2b.tick = tick + s * 640 + 256;
        g35.tick = tick + s * 640 + 512;
        gemm_sk<<<gH2, 512, 0, stream>>>(g1);
        gemm_sk<<<gH5, 512, 0, stream>>>(g2);
        gemm_sk<<<gH2, 512, 0, stream>>>(g2b);   // Kk@Wv2 + fused RWKV mix -> Acat35
        gemm_sk<<<gD4, 512, 0, stream>>>(g35);   // [Rw|V2]@W35: drift + Acat + ticket
    }

    // ---- final commit step (no done guard; ORIGINAL l_state) ----
    float* stateOut = dout + BD_;

    GemmP f1p = g1;
    f1p.done = nullptr; f1p.lstate = lstate; f1p.stateOut = stateOut;
    f1p.tick = tick + 8 * 640;
    gemm_sk<<<gH2, 512, 0, stream>>>(f1p);

    GemmP f2p = g2; f2p.done = nullptr;
    gemm_sk<<<gH5, 512, 0, stream>>>(f2p);

    GemmP f2bp = g2b;
    f2bp.done = nullptr; f2bp.lstate = lstate; f2bp.stateOut = stateOut;
    f2bp.tick = tick + 8 * 640 + 256;
    gemm_sk<<<gH2, 512, 0, stream>>>(f2bp);

    GemmP f35p = {};
    f35p.A[0] = Acat35; f35p.W[0] = W35F; f35p.mode[0] = M_FINAL;
    f35p.M = Bb; f35p.N = Dd; f35p.K = 4096; f35p.S = 4; f35p.part = part;
    f35p.tick = tick + 8 * 640 + 512;
    f35p.enc = enc; f35p.bout = b_out; f35p.dout = dout;
    gemm_sk<<<gD4, 512, 0, stream>>>(f35p);

    tailk<<<(BD_ + 255) / 256, 256, 0, stream>>>(scal, drift, dout);
}

// Round 5
// 1604.615 us; speedup vs baseline: 3.6569x; 3.6569x over previous
//
#include <hip/hip_runtime.h>
#include <hip/hip_bf16.h>

#define Bb 512
#define Dd 1024
#define Hh 2048
#define BH_ (Bb*Hh)
#define BD_ (Bb*Dd)

typedef unsigned short u16;
typedef __attribute__((ext_vector_type(8))) short short8;
typedef __attribute__((ext_vector_type(4))) float f32x4;

enum { M_F32 = 0, M_IN, M_SIG, M_SQRELU, M_MIX, M_BF16, M_DRIFT, M_FINAL };

struct GemmP {
    const u16* A[5];
    const u16* W[5];     // transposed weights, N x K, bf16
    void* dst[5];
    int mode[5];
    int M, N, K;
    int dstride;         // dst row stride for M_BF16
    const int* done;
    // epilogue extras
    const float* bias;
    const float* mk; const float* mv; const float* mr; const float* mk2v; const float* mr2v;
    float* xx; float* cc;                 // planar shadow state (loop)
    const float* lstate;                  // original interleaved state (final) or null
    float* liF;                           // Li plane (loop)
    float* stateOut;                      // d_out next_state base (final)
    u16 *o1, *o2, *o3, *o4, *o5;          // Xk,Xv,Xr,Xk2,Xr2
    // fused-mix extras (M_MIX)
    const float* Kp; const float* Vp; const float* Rp;
    float* aa; float* bbp; float* ppp;
    const float* Li;
    const float* tf; const float* td;
    const float* R2;
    u16* acat35;                          // [512][4096]: Rw | V2 (bf16), mix writes both
    float* drift; float* accAbs; float* accSq;
    float* scal; int nticket;             // ticket-folded stepfin (M_DRIFT only)
    const float* enc; const float* bout; float* dout;
    const float* sc; u16* acat;           // M_DRIFT maintains Acat's sc+drift half
};

#define GLDS16(gp, lp) __builtin_amdgcn_global_load_lds( \
    (const __attribute__((address_space(1))) void*)(gp), \
    (__attribute__((address_space(3))) void*)(lp), 16, 0, 0)

// ---- 64x64 tile, 512 threads (8 waves), in-block split-K x2 ----
// K loop: 3 LDS buffer pairs, 2-slab-deep GLDS prefetch, ONE raw s_barrier
// per slab preceded by a COUNTED s_waitcnt vmcnt(2) (never 0 in the loop,
// T4) so prefetched loads stay in flight across the barrier. Staging uses
// global_load_lds dwordx4 with XOR-swizzled source chunks (conflict-free
// ds_read_b128). Partials merged through LDS; kg==0 waves run the epilogue.
// blockIdx is XCD-swizzled (bijective): each XCD owns nbx/8 consecutive
// n-columns so B panels are L2-resident per XCD (T1).
__global__ __launch_bounds__(512, 6) void gemm_sk(GemmP p) {
    if (p.done && *(volatile const int*)p.done) return;
    const int z = blockIdx.z;
    const u16* __restrict__ A = p.A[z];
    const u16* __restrict__ W = p.W[z];
    const int Kd = p.K;

    // bijective XCD swizzle: xcd c <- n-column group c (B-panel locality)
    const int nbx = gridDim.x;
    const int P = nbx >> 3;                        // n-cols per XCD (grids are /8)
    const int local = (int)blockIdx.y * nbx + (int)blockIdx.x;
    const int cxcd = local & 7, j = local >> 3;
    const int bx = cxcd * P + (j % P);
    const int by = j / P;
    const int m0 = by * 64, n0 = bx * 64;

    __shared__ alignas(16) u16 smem[6][64 * 64];   // A0..A2, B0..B2 = 48 KiB

    const int t = threadIdx.x;
    const int l = t & 63, w = t >> 6;              // 8 waves
    const int lane16 = l & 15, quad = l >> 4;
    const int wq = w & 3, kg = w >> 2;
    const int wm = wq & 1, wn = wq >> 1;

    // staging: thread t owns row t>>3, linear 16B chunk t&7, swizzled source
    const int srow = t >> 3, sc8 = t & 7;
    const int scs = sc8 ^ (srow & 7);
    const u16* ag = A + (size_t)(m0 + srow) * Kd + scs * 8;
    const u16* bg = W + (size_t)(n0 + srow) * Kd + scs * 8;

    f32x4 zero = {0.f, 0.f, 0.f, 0.f};
    f32x4 acc[2][2];
    acc[0][0] = zero; acc[0][1] = zero; acc[1][0] = zero; acc[1][1] = zero;

    const int nslab = Kd >> 6;
    // prologue: stage slabs 0 and 1 (no barrier; iter 0's vmcnt+barrier covers)
    GLDS16(ag,      &smem[0][512 * w]);
    GLDS16(bg,      &smem[3][512 * w]);
    GLDS16(ag + 64, &smem[1][512 * w]);
    GLDS16(bg + 64, &smem[4][512 * w]);

    int bcur = 0;
    for (int t2 = 0; t2 < nslab; ++t2) {
        // counted wait: slab t2's 2 loads are the oldest; leave the 2 newer
        // (slab t2+1) in flight. Only the last slab drains to 0.
        if (t2 < nslab - 1) { asm volatile("s_waitcnt vmcnt(2)" ::: "memory"); }
        else                { asm volatile("s_waitcnt vmcnt(0)" ::: "memory"); }
        __builtin_amdgcn_sched_barrier(0);
        __builtin_amdgcn_s_barrier();
        __builtin_amdgcn_sched_barrier(0);

        const u16* As = smem[bcur];
        const u16* Bs = smem[3 + bcur];
        const int cg = kg * 4 + quad;              // this wave's 16B chunk in slab
        const int ra0 = wm * 32 + lane16, ra1 = ra0 + 16;
        const int rb0 = wn * 32 + lane16, rb1 = rb0 + 16;
        short8 af0 = *(const short8*)(const void*)&As[ra0 * 64 + ((cg ^ (ra0 & 7)) << 3)];
        short8 af1 = *(const short8*)(const void*)&As[ra1 * 64 + ((cg ^ (ra1 & 7)) << 3)];
        short8 bf0 = *(const short8*)(const void*)&Bs[rb0 * 64 + ((cg ^ (rb0 & 7)) << 3)];
        short8 bf1 = *(const short8*)(const void*)&Bs[rb1 * 64 + ((cg ^ (rb1 & 7)) << 3)];

        // stage slab t2+2 into buf (t2+2)%3 == the buffer read at t2-1
        // (safe: all waves passed this iter's barrier => t2-1 reads complete)
        if (t2 + 2 < nslab) {
            const int bst = (bcur == 0) ? 2 : bcur - 1;
            GLDS16(ag + (size_t)(t2 + 2) * 64, &smem[bst][512 * w]);
            GLDS16(bg + (size_t)(t2 + 2) * 64, &smem[3 + bst][512 * w]);
        }

        acc[0][0] = __builtin_amdgcn_mfma_f32_16x16x32_bf16(af0, bf0, acc[0][0], 0, 0, 0);
        acc[0][1] = __builtin_amdgcn_mfma_f32_16x16x32_bf16(af0, bf1, acc[0][1], 0, 0, 0);
        acc[1][0] = __builtin_amdgcn_mfma_f32_16x16x32_bf16(af1, bf0, acc[1][0], 0, 0, 0);
        acc[1][1] = __builtin_amdgcn_mfma_f32_16x16x32_bf16(af1, bf1, acc[1][1], 0, 0, 0);
        __builtin_amdgcn_sched_barrier(0);
        bcur = (bcur == 2) ? 0 : bcur + 1;
    }
    __syncthreads();   // full drain before smem reuse as reduction buffer

    // ---- cross-wave-group partial merge via LDS (17-float pad per lane) ----
    float* red = (float*)smem;
    const int rbase = wq * 1088 + l * 17;
    if (kg == 1) {
#pragma unroll
        for (int sm = 0; sm < 2; ++sm)
#pragma unroll
            for (int sn = 0; sn < 2; ++sn)
#pragma unroll
                for (int i = 0; i < 4; ++i)
                    red[rbase + (sm * 2 + sn) * 4 + i] = acc[sm][sn][i];
    }
    __syncthreads();

    const int mode = p.mode[z];
    float sabs = 0.f, ssq = 0.f;
    if (kg == 0) {
#pragma unroll
        for (int sm = 0; sm < 2; ++sm)
#pragma unroll
            for (int sn = 0; sn < 2; ++sn)
#pragma unroll
                for (int i = 0; i < 4; ++i) {
                    const int m = m0 + wm * 32 + sm * 16 + quad * 4 + i;
                    const int n = n0 + wn * 32 + sn * 16 + lane16;
                    const size_t idx = (size_t)m * p.N + n;
                    const float v = acc[sm][sn][i] + red[rbase + (sm * 2 + sn) * 4 + i];
                    if (mode == M_F32) {
                        ((float*)p.dst[z])[idx] = v;
                    } else if (mode == M_IN) {
                        float li = fminf(fmaxf(v + p.bias[n], -50.f), 50.f);
                        float xxv, ccv;
                        if (p.lstate) { xxv = p.lstate[idx * 5 + 0]; ccv = p.lstate[idx * 5 + 4]; }
                        else { xxv = p.xx[idx]; ccv = p.cc[idx]; }
                        float mk = p.mk[n], mv = p.mv[n], mr = p.mr[n], mk2 = p.mk2v[n], mr2 = p.mr2v[n];
                        ((__hip_bfloat16*)p.o1)[idx] = __float2bfloat16(li * mk + xxv * (1.f - mk));
                        ((__hip_bfloat16*)p.o2)[idx] = __float2bfloat16(li * mv + xxv * (1.f - mv));
                        ((__hip_bfloat16*)p.o3)[idx] = __float2bfloat16(li * mr + xxv * (1.f - mr));
                        ((__hip_bfloat16*)p.o4)[idx] = __float2bfloat16(li * mk2 + ccv * (1.f - mk2));
                        ((__hip_bfloat16*)p.o5)[idx] = __float2bfloat16(li * mr2 + ccv * (1.f - mr2));
                        if (p.lstate) { p.stateOut[idx * 5 + 0] = li; p.stateOut[idx * 5 + 4] = li; }
                        else p.liF[idx] = li;
                    } else if (mode == M_SIG) {
                        ((float*)p.dst[z])[idx] = 1.f / (1.f + __expf(-v));
                    } else if (mode == M_SQRELU) {
                        float r = fmaxf(v, 0.f);
                        ((__hip_bfloat16*)p.dst[z])[idx] = __float2bfloat16(r * r);
                    } else if (mode == M_BF16) {
                        ((__hip_bfloat16*)p.dst[z])[(size_t)m * p.dstride + n] = __float2bfloat16(v);
                    } else if (mode == M_MIX) {
                        // fused RWKV wkv + state update; writes Rw and V2 into acat35
                        float k = p.Kp[idx], vv = p.Vp[idx], rpre = p.Rp[idx];
                        float a, b, P5;
                        if (p.lstate) { a = p.lstate[idx * 5 + 1]; b = p.lstate[idx * 5 + 2]; P5 = p.lstate[idx * 5 + 3]; }
                        else { a = p.aa[idx]; b = p.bbp[idx]; P5 = p.ppp[idx]; }
                        float r = 1.f / (1.f + __expf(-rpre));
                        float ww = p.tf[n] + k;
                        float q = fmaxf(P5, ww);
                        float e1 = __expf(P5 - q), e2 = __expf(ww - q);
                        float wkv = (e1 * a + e2 * vv) / (e1 * b + e2);
                        const size_t i35 = (size_t)m * 4096 + n;
                        ((__hip_bfloat16*)p.acat35)[i35] = __float2bfloat16(r * wkv);
                        ((__hip_bfloat16*)p.acat35)[i35 + 2048] = __float2bfloat16(p.R2[idx] * v);
                        float ww2 = P5 - __expf(p.td[n]);
                        float q2 = fmaxf(ww2, k);
                        float e1b = __expf(ww2 - q2), e2b = __expf(k - q2);
                        float na  = fminf(fmaxf(e1b * a + e2b * vv, -50.f), 50.f);
                        float nb2 = fminf(fmaxf(e1b * b + e2b, -50.f), 50.f);
                        float nq  = fminf(fmaxf(q2, -50.f), 50.f);
                        if (p.lstate) {
                            p.stateOut[idx * 5 + 1] = na; p.stateOut[idx * 5 + 2] = nb2; p.stateOut[idx * 5 + 3] = nq;
                        } else {
                            p.aa[idx] = na; p.bbp[idx] = nb2; p.ppp[idx] = nq;
                            float li = p.Li[idx];
                            p.xx[idx] = li; p.cc[idx] = li;
                        }
                    } else if (mode == M_DRIFT) {
                        float d = tanhf(v);
                        float nd = fminf(fmaxf(p.drift[idx] + d, -5.f), 5.f);
                        p.drift[idx] = nd;
                        ((__hip_bfloat16*)p.acat)[(size_t)m * 2048 + 1024 + n] = __float2bfloat16(p.sc[idx] + nd);
                        sabs += fabsf(d);
                        ssq += nd * nd;
                    } else { // M_FINAL
                        p.dout[idx] = p.enc[idx] + v + p.bout[n];
                    }
                }
    }

    if (mode == M_DRIFT) {
        if (kg == 0) {
#pragma unroll
            for (int off = 32; off > 0; off >>= 1) {
                sabs += __shfl_down(sabs, off, 64);
                ssq += __shfl_down(ssq, off, 64);
            }
            if (l == 0) { atomicAdd(p.accAbs, sabs); atomicAdd(p.accSq, ssq); }
        }
        __syncthreads();
        if (t == 0) {   // last-block ticket performs the per-step scalar finalize
            __threadfence();
            int vtk = atomicAdd((int*)(p.scal + 5), 1);
            if (vtk == p.nticket - 1) {
                volatile float* s = p.scal;
                float hinge = fminf(fmaxf(s[4] / (float)Bb - 0.1f, 0.f), 100.f);
                s[1] = s[1] + hinge;
                s[2] = s[2] + 1.f;
                if (s[3] / (float)BD_ < 0.01f) ((volatile int*)p.scal)[0] = 1;
                s[3] = 0.f; s[4] = 0.f;
                ((volatile int*)p.scal)[5] = 0;
            }
        }
    }
}

// ---------------- z-batched transpose f32 (KxN) -> bf16 (NxK) ----------------
struct TP { const float* src[7]; u16* dst[7]; int K; int N; };

__global__ void transposeWz(TP tp) {
    __shared__ float tile[32][33];
    const float* __restrict__ src = tp.src[blockIdx.z];
    u16* __restrict__ dst = tp.dst[blockIdx.z];
    int kt = blockIdx.y * 32, nt = blockIdx.x * 32;
    int tx = threadIdx.x, ty = threadIdx.y;
#pragma unroll
    for (int j = 0; j < 4; j++)
        tile[ty + j * 8][tx] = src[(size_t)(kt + ty + j * 8) * tp.N + nt + tx];
    __syncthreads();
    __hip_bfloat16* d = (__hip_bfloat16*)dst;
#pragma unroll
    for (int j = 0; j < 4; j++)
        d[(size_t)(nt + ty + j * 8) * tp.K + kt + tx] = __float2bfloat16(tile[tx][ty + j * 8]);
}

// ---------------- f32 -> bf16 row-major cast (Wo) ----------------
__global__ void castW(const float* __restrict__ src, u16* __restrict__ dst, int nelem) {
    int i = blockIdx.x * 256 + threadIdx.x;
    if (i < nelem) ((__hip_bfloat16*)dst)[i] = __float2bfloat16(src[i]);
}

// ---------------- copy WdT/WoutT into the K>=2048 half of W35/W35F ----------------
struct CP { const u16* src[2]; u16* dst[2]; };
__global__ void copyTail(CP cp) {
    int i = blockIdx.x * 256 + threadIdx.x;     // over 1024*2048
    if (i >= Dd * Hh) return;
    const u16* s = cp.src[blockIdx.z];
    u16* d = cp.dst[blockIdx.z];
    int m = i >> 11, k = i & 2047;
    d[(size_t)m * 4096 + 2048 + k] = s[i];
}

// ---------------- per-call init: planarize state, drift, scalars, Acat ----------------
__global__ void initstate(const float* __restrict__ lstate, const float* __restrict__ idrift,
                          const float* __restrict__ enc, const float* __restrict__ sc,
                          float* xx, float* aa, float* bb, float* pp, float* cc,
                          float* drift, float* scal, u16* acat) {
    int i = blockIdx.x * 256 + threadIdx.x;
    if (i < BH_) {
        const float* s = lstate + (size_t)i * 5;
        xx[i] = s[0]; aa[i] = s[1]; bb[i] = s[2]; pp[i] = s[3]; cc[i] = s[4];
    }
    if (i < BD_) {
        drift[i] = idrift[i];
        int m = i >> 10, d = i & 1023;
        __hip_bfloat16* Ab = (__hip_bfloat16*)acat;
        Ab[(size_t)m * 2048 + d] = __float2bfloat16(enc[i]);
        Ab[(size_t)m * 2048 + 1024 + d] = __float2bfloat16(sc[i] + idrift[i]);
    }
    if (i == 0) {
        ((int*)scal)[0] = 0; scal[1] = 0.f; scal[2] = 0.f; scal[3] = 0.f; scal[4] = 0.f;
        ((int*)scal)[5] = 0;
    }
}

// ---------------- tail: commitment scalar + drift copy ----------------
__global__ void tailk(const float* __restrict__ scal, const float* __restrict__ drift, float* __restrict__ dout) {
    int i = blockIdx.x * 256 + threadIdx.x;
    const size_t OC = (size_t)BD_ + (size_t)5 * BH_;
    if (i == 0) dout[OC] = scal[1] / fmaxf(scal[2], 1.f);
    if (i < BD_) dout[OC + 1 + i] = drift[i];
}

extern "C" void kernel_launch(void* const* d_in, const int* in_sizes, int n_in,
                              void* d_out, int out_size, void* d_ws, size_t ws_size,
                              hipStream_t stream) {
    const float* enc    = (const float*)d_in[0];
    const float* sc     = (const float*)d_in[1];
    const float* lstate = (const float*)d_in[2];
    const float* idrift = (const float*)d_in[3];
    const float* Win    = (const float*)d_in[4];
    const float* b_in   = (const float*)d_in[5];
    const float* Wdrift = (const float*)d_in[6];
    const float* Wout   = (const float*)d_in[7];
    const float* b_out  = (const float*)d_in[8];
    const float* mix_k  = (const float*)d_in[9];
    const float* mix_v  = (const float*)d_in[10];
    const float* mix_r  = (const float*)d_in[11];
    const float* mix_k2 = (const float*)d_in[12];
    const float* mix_r2 = (const float*)d_in[13];
    const float* tdec   = (const float*)d_in[14];
    const float* tfirst = (const float*)d_in[15];
    const float* Wk  = (const float*)d_in[16];
    const float* Wv  = (const float*)d_in[17];
    const float* Wr  = (const float*)d_in[18];
    const float* Wo  = (const float*)d_in[19];
    const float* Wk2 = (const float*)d_in[20];
    const float* Wv2 = (const float*)d_in[21];
    const float* Wr2 = (const float*)d_in[22];
    float* dout = (float*)d_out;

    const size_t BHs = (size_t)Bb * Hh;
    const size_t BDs = (size_t)Bb * Dd;

    const size_t need_f32 = 10 * BHs + BDs + 16;
    const size_t need_u16 = (size_t)2 * Dd * Hh + 6 * (size_t)Hh * Hh + 2 * (size_t)Hh * Dd
                          + 2 * (size_t)Dd * 4096 + 7 * BHs + (size_t)Bb * 4096;
    const size_t need_bytes = need_f32 * 4 + need_u16 * 2;
    if (ws_size < need_bytes) return;

    float* f = (float*)d_ws;
    float* xx  = f;
    float* aa  = xx + BHs;
    float* bbp = aa + BHs;
    float* ppp = bbp + BHs;
    float* cc  = ppp + BHs;
    float* Li  = cc + BHs;
    float* Kp  = Li + BHs;
    float* Vp  = Kp + BHs;
    float* Rp  = Vp + BHs;
    float* R2  = Rp + BHs;
    float* drift = R2 + BHs;
    float* scal  = drift + BDs;
    u16* u = (u16*)(scal + 16);
    u16* WinT  = u; u += (size_t)2 * Dd * Hh;
    u16* WkT   = u; u += (size_t)Hh * Hh;
    u16* WvT   = u; u += (size_t)Hh * Hh;
    u16* WrT   = u; u += (size_t)Hh * Hh;
    u16* Wk2T  = u; u += (size_t)Hh * Hh;
    u16* Wv2T  = u; u += (size_t)Hh * Hh;
    u16* Wr2T  = u; u += (size_t)Hh * Hh;
    u16* WdT   = u; u += (size_t)Hh * Dd;
    u16* WoutT = u; u += (size_t)Hh * Dd;
    u16* W35   = u; u += (size_t)Dd * 4096;   // [1024][4096]: (Wo@Wd)^T | WdT
    u16* W35F  = u; u += (size_t)Dd * 4096;   // [1024][4096]: (Wo@Wout)^T | WoutT
    u16* Acat  = u; u += BHs;                 // [512][2048]: enc | sc+drift
    u16* Xk    = u; u += BHs;
    u16* Xv    = u; u += BHs;
    u16* Xr    = u; u += BHs;
    u16* Xk2   = u; u += BHs;
    u16* Xr2   = u; u += BHs;
    u16* Kk    = u; u += BHs;
    u16* Acat35 = u; u += (size_t)Bb * 4096;  // [512][4096]: Rw | V2
    u16* Wo_bf = Xk;                          // alias: Wo cast (Xk..Xk2), dead before step 0

    int* doneptr = (int*)scal;
    float* accAbs = scal + 3;
    float* accSq  = scal + 4;

    dim3 tb(32, 8);
    TP tpa = {};
    tpa.src[0] = Wk;  tpa.dst[0] = WkT;
    tpa.src[1] = Wv;  tpa.dst[1] = WvT;
    tpa.src[2] = Wr;  tpa.dst[2] = WrT;
    tpa.src[3] = Wk2; tpa.dst[3] = Wk2T;
    tpa.src[4] = Wv2; tpa.dst[4] = Wv2T;
    tpa.src[5] = Wr2; tpa.dst[5] = Wr2T;
    tpa.K = Hh; tpa.N = Hh;
    transposeWz<<<dim3(Hh / 32, Hh / 32, 6), tb, 0, stream>>>(tpa);
    TP tpb = {};
    tpb.src[0] = Win; tpb.dst[0] = WinT; tpb.K = 2 * Dd; tpb.N = Hh;
    transposeWz<<<dim3(Hh / 32, (2 * Dd) / 32, 1), tb, 0, stream>>>(tpb);
    TP tpc = {};
    tpc.src[0] = Wdrift; tpc.dst[0] = WdT;
    tpc.src[1] = Wout;   tpc.dst[1] = WoutT;
    tpc.K = Hh; tpc.N = Dd;
    transposeWz<<<dim3(Dd / 32, Hh / 32, 2), tb, 0, stream>>>(tpc);

    castW<<<(Hh * Hh + 255) / 256, 256, 0, stream>>>(Wo, Wo_bf, Hh * Hh);

    initstate<<<(BH_ + 255) / 256, 256, 0, stream>>>(lstate, idrift, enc, sc,
                                                     xx, aa, bbp, ppp, cc, drift, scal, Acat);

    // ---- one-time weight products: W35 = [(Wo@Wd)^T | WdT], W35F = [(Wo@Wout)^T | WoutT] ----
    GemmP pp = {};
    pp.A[0] = WdT;   pp.W[0] = Wo_bf; pp.mode[0] = M_BF16; pp.dst[0] = W35;
    pp.A[1] = WoutT; pp.W[1] = Wo_bf; pp.mode[1] = M_BF16; pp.dst[1] = W35F;
    pp.M = Dd; pp.N = Hh; pp.K = Hh; pp.dstride = 4096;
    gemm_sk<<<dim3(Hh / 64, Dd / 64, 2), 512, 0, stream>>>(pp);

    CP cpt = {};
    cpt.src[0] = WdT;   cpt.dst[0] = W35;
    cpt.src[1] = WoutT; cpt.dst[1] = W35F;
    copyTail<<<dim3((Dd * Hh + 255) / 256, 1, 2), 256, 0, stream>>>(cpt);

    // ---- GEMM descriptors ----
    GemmP g1 = {};
    g1.A[0] = Acat; g1.W[0] = WinT; g1.mode[0] = M_IN;
    g1.M = Bb; g1.N = Hh; g1.K = 2 * Dd;
    g1.done = doneptr;
    g1.bias = b_in; g1.mk = mix_k; g1.mv = mix_v; g1.mr = mix_r; g1.mk2v = mix_k2; g1.mr2v = mix_r2;
    g1.xx = xx; g1.cc = cc; g1.liF = Li;
    g1.o1 = Xk; g1.o2 = Xv; g1.o3 = Xr; g1.o4 = Xk2; g1.o5 = Xr2;

    GemmP g2 = {};
    g2.A[0] = Xk;  g2.W[0] = WkT;  g2.mode[0] = M_F32;    g2.dst[0] = Kp;
    g2.A[1] = Xv;  g2.W[1] = WvT;  g2.mode[1] = M_F32;    g2.dst[1] = Vp;
    g2.A[2] = Xr;  g2.W[2] = WrT;  g2.mode[2] = M_F32;    g2.dst[2] = Rp;
    g2.A[3] = Xr2; g2.W[3] = Wr2T; g2.mode[3] = M_SIG;    g2.dst[3] = R2;
    g2.A[4] = Xk2; g2.W[4] = Wk2T; g2.mode[4] = M_SQRELU; g2.dst[4] = Kk;
    g2.M = Bb; g2.N = Hh; g2.K = Hh;
    g2.done = doneptr;

    GemmP g2b = {};
    g2b.A[0] = Kk; g2b.W[0] = Wv2T; g2b.mode[0] = M_MIX;
    g2b.M = Bb; g2b.N = Hh; g2b.K = Hh;
    g2b.done = doneptr;
    g2b.Kp = Kp; g2b.Vp = Vp; g2b.Rp = Rp;
    g2b.aa = aa; g2b.bbp = bbp; g2b.ppp = ppp;
    g2b.xx = xx; g2b.cc = cc; g2b.Li = Li;
    g2b.tf = tfirst; g2b.td = tdec;
    g2b.R2 = R2; g2b.acat35 = Acat35;

    GemmP g35 = {};
    g35.A[0] = Acat35; g35.W[0] = W35; g35.mode[0] = M_DRIFT;
    g35.M = Bb; g35.N = Dd; g35.K = 4096;
    g35.done = doneptr;
    g35.drift = drift; g35.accAbs = accAbs; g35.accSq = accSq;
    g35.scal = scal; g35.nticket = (Dd / 64) * (Bb / 64);   // 128
    g35.sc = sc; g35.acat = Acat;

    dim3 gH(Hh / 64, Bb / 64, 1);      // 32 x 8 = 256 blocks
    dim3 gH5(Hh / 64, Bb / 64, 5);     // 1280 blocks
    dim3 gD(Dd / 64, Bb / 64, 1);      // 16 x 8 = 128 blocks

    for (int s = 0; s < 8; ++s) {
        gemm_sk<<<gH,  512, 0, stream>>>(g1);
        gemm_sk<<<gH5, 512, 0, stream>>>(g2);
        gemm_sk<<<gH,  512, 0, stream>>>(g2b);   // Kk@Wv2 + fused RWKV mix -> Acat35
        gemm_sk<<<gD,  512, 0, stream>>>(g35);   // [Rw|V2]@W35: drift + Acat + ticket
    }

    // ---- final commit step (no done guard; ORIGINAL l_state) ----
    float* stateOut = dout + BD_;

    GemmP f1p = g1;
    f1p.done = nullptr; f1p.lstate = lstate; f1p.stateOut = stateOut;
    gemm_sk<<<gH, 512, 0, stream>>>(f1p);

    GemmP f2p = g2; f2p.done = nullptr;
    gemm_sk<<<gH5, 512, 0, stream>>>(f2p);

    GemmP f2bp = g2b;
    f2bp.done = nullptr; f2bp.lstate = lstate; f2bp.stateOut = stateOut;
    gemm_sk<<<gH, 512, 0, stream>>>(f2bp);

    GemmP f35p = {};
    f35p.A[0] = Acat35; f35p.W[0] = W35F; f35p.mode[0] = M_FINAL;
    f35p.M = Bb; f35p.N = Dd; f35p.K = 4096;
    f35p.enc = enc; f35p.bout = b_out; f35p.dout = dout;
    gemm_sk<<<gD, 512, 0, stream>>>(f35p);

    tailk<<<(BD_ + 255) / 256, 256, 0, stream>>>(scal, drift, dout);
}